// Round 6
// baseline (181.928 us; speedup 1.0000x reference)
//
#include <hip/hip_runtime.h>

typedef unsigned short ushort_t;
using bf16x8 = __attribute__((ext_vector_type(8))) short;
using f32x16 = __attribute__((ext_vector_type(16))) float;

#define KT 27
#define NV 65536

__device__ inline unsigned short f2bf(float f) {
  unsigned int u = __builtin_bit_cast(unsigned int, f);
  u += 0x7fffu + ((u >> 16) & 1u);
  return (unsigned short)(u >> 16);
}
__device__ inline float b2f(ushort_t u) {
  unsigned int x = ((unsigned int)u) << 16;
  return __builtin_bit_cast(float, x);
}

// compile-time loop: every iteration index is constexpr.
template <int I, int N, typename F>
__device__ __forceinline__ void static_for(F&& f) {
  if constexpr (I < N) {
    f.template operator()<I>();
    static_for<I + 1, N>(static_cast<F&&>(f));
  }
}

// merged prep: statsp+zrow zero (block 0), x fp32->bf16 (blocks 0..4095),
// W1,W2 [k][c][d] -> per-lane MFMA B frags (blocks 4096..5823)
// Wf[(k*8 + ks*2 + ct)*512 + l*8 + j] = bf16(W[k][ks*16 + (l>>5)*8 + j][ct*32 + (l&31)])
__global__ __launch_bounds__(256) void k_prep(const float* __restrict__ x,
                                              const float* __restrict__ W1,
                                              const float* __restrict__ W2,
                                              ushort_t* __restrict__ xb,
                                              ushort_t* __restrict__ Wf1,
                                              ushort_t* __restrict__ Wf2,
                                              float* __restrict__ statsp) {
  int b = blockIdx.x;
  int t = threadIdx.x;
  if (b == 0) {                    // 256 stats floats + 256 floats of zero-row pad
    statsp[t] = 0.f;               // convs run after this dispatch
    statsp[256 + t] = 0.f;         // zrow: gather target for inactive taps
  }
  if (b < 4096) {
    int i = b * 256 + t;  // float4 index
    float4 v = ((const float4*)x)[i];
    ushort4 o;
    o.x = f2bf(v.x); o.y = f2bf(v.y); o.z = f2bf(v.z); o.w = f2bf(v.w);
    ((ushort4*)xb)[i] = o;
  } else {
    int e = (b - 4096) * 256 + t;  // < 442368
    const float* W = W1; ushort_t* Wf = Wf1;
    if (e >= 221184) { e -= 221184; W = W2; Wf = Wf2; }
    int j = e & 7, l = (e >> 3) & 63, u = (e >> 9) & 7, k = e >> 12;
    int ks = u >> 1, ct = u & 1;
    int c = ks * 16 + (l >> 5) * 8 + j;
    int d = ct * 32 + (l & 31);
    Wf[e] = f2bf(W[(k << 12) + (c << 6) + d]);
  }
}

// Gather-GEMM conv, 32x32x16 MFMA, barrier-free K-loop.
// R6 structure: A gathered via global_load_lds (fire-and-forget LDS-DMA;
// per-lane GLOBAL address = the gather; LDS dest = wave-uniform base + lane*16)
// into a per-wave 4-slot LDS ring, issued 3 taps ahead. B triple-buffered in
// VGPRs, issued 2 taps ahead. A is consumed via INLINE-ASM ds_read_b128
// (invisible to the compiler's waitcnt pass -> no auto vmcnt(0)); arrival is
// guaranteed by OUR counted s_waitcnt vmcnt(N): issue order is pinned by
// sched_barriers, ops-newer-than-B(k) = A(k+1)+B(k+1)+A(k+2)+B(k+2)+A(k+3)
// = 28 steady (24/12/0 in the tail). lgkmcnt(0)+sched_barrier(0) precede the
// MFMAs (asm ds_read hoist hazard, guide rule #18).
// LDS: ring 64KB + rulebook 13.8KB + red 2KB = 81,408B -> exactly 2 blocks/CU.
template<bool OBF16>
__global__ __launch_bounds__(256)
__attribute__((amdgpu_waves_per_eu(2, 2)))
void k_conv(const ushort_t* __restrict__ src,  // [N][64] bf16
            const int* __restrict__ nbr,       // [N][27]
            const ushort_t* __restrict__ Wf,
            const ushort_t* __restrict__ zrow, // 1KB of zeros
            void* __restrict__ houtv,          // [N][64]
            float* __restrict__ gsum,
            float* __restrict__ gsq) {
  __shared__ alignas(16) ushort_t As[4][4][2048];  // [wave][slot][ks*512 + lane*8], 64 KB
  __shared__ int nb_l[4][32 * KT];                 // per-wave rulebook rows, 13.8 KB
  __shared__ float red[2][4][64];                  // stats reduce, 2 KB

  const int t = threadIdx.x;
  const int lane = t & 63;
  const int w = t >> 6;
  const int hh = lane >> 5;
  const int r31 = lane & 31;
  const int wbase = blockIdx.x * 128 + w * 32;

  int* nbw = &nb_l[w][0];
  {
    const int* nbg = nbr + wbase * KT;
    for (int e = lane; e < 32 * KT; e += 64) nbw[e] = nbg[e];  // wave-local: no barrier
  }

  f32x16 acc0 = {0,0,0,0,0,0,0,0,0,0,0,0,0,0,0,0};
  f32x16 acc1 = {0,0,0,0,0,0,0,0,0,0,0,0,0,0,0,0};

  struct BTap { bf16x8 b0, b1, b2, b3, b4, b5, b6, b7; };  // 32 VGPRs, by-value only
  BTap B0, B1, B2;   // triple buffer: B(j) lives in slot j%3

  const ushort_t* srcl = src + hh * 8;   // lane's K-half offset folded into base
  const ushort_t* zl = zrow + hh * 8;

  // lane-specific LDS byte address of this wave's ring base (+lane*16)
  const unsigned abase =
      (unsigned)(unsigned long long)(__attribute__((address_space(3))) ushort_t*)&As[w][0][0]
      + (unsigned)(lane * 16);

  // Issue tap k's 4 LDS-DMA gathers (slot k&3). Per-lane global address; HW
  // writes lane's 16B at slotbase + ks*1024 + lane*16.
  auto issueA = [&](int k) {
    int idx = nbw[r31 * KT + k];
    const ushort_t* p = (idx >= 0) ? (srcl + ((long)idx << 6)) : zl;
    ushort_t* lb = &As[w][k & 3][0];
#pragma unroll
    for (int ks = 0; ks < 4; ++ks)
      __builtin_amdgcn_global_load_lds(
          (const __attribute__((address_space(1))) void*)(p + ks * 16),
          (__attribute__((address_space(3))) void*)(lb + ks * 512), 16, 0, 0);
  };
  auto ldB = [&](int k) -> BTap {
    const ushort_t* p = Wf + k * 4096 + lane * 8;
    BTap b;
    b.b0 = *(const bf16x8*)(p);
    b.b1 = *(const bf16x8*)(p + 512);
    b.b2 = *(const bf16x8*)(p + 1024);
    b.b3 = *(const bf16x8*)(p + 1536);
    b.b4 = *(const bf16x8*)(p + 2048);
    b.b5 = *(const bf16x8*)(p + 2560);
    b.b6 = *(const bf16x8*)(p + 3072);
    b.b7 = *(const bf16x8*)(p + 3584);
    return b;
  };
  auto setB = [&]<int j>() {
    BTap tmp = ldB(j);
    if constexpr (j % 3 == 0) B0 = tmp;
    else if constexpr (j % 3 == 1) B1 = tmp;
    else B2 = tmp;
  };
  auto compute = [&](bf16x8 a0, bf16x8 a1, bf16x8 a2, bf16x8 a3, const BTap& b) {
    acc0 = __builtin_amdgcn_mfma_f32_32x32x16_bf16(a0, b.b0, acc0, 0, 0, 0);
    acc1 = __builtin_amdgcn_mfma_f32_32x32x16_bf16(a0, b.b1, acc1, 0, 0, 0);
    acc0 = __builtin_amdgcn_mfma_f32_32x32x16_bf16(a1, b.b2, acc0, 0, 0, 0);
    acc1 = __builtin_amdgcn_mfma_f32_32x32x16_bf16(a1, b.b3, acc1, 0, 0, 0);
    acc0 = __builtin_amdgcn_mfma_f32_32x32x16_bf16(a2, b.b4, acc0, 0, 0, 0);
    acc1 = __builtin_amdgcn_mfma_f32_32x32x16_bf16(a2, b.b5, acc1, 0, 0, 0);
    acc0 = __builtin_amdgcn_mfma_f32_32x32x16_bf16(a3, b.b6, acc0, 0, 0, 0);
    acc1 = __builtin_amdgcn_mfma_f32_32x32x16_bf16(a3, b.b7, acc1, 0, 0, 0);
  };

#define SB __builtin_amdgcn_sched_barrier(0)
#define DSR(dst, OFS) asm volatile("ds_read_b128 %0, %1 offset:" OFS : "=v"(dst) : "v"(abase));

  // prologue (issue order pinned; counts depend on it):
  // A(0) | B(0) | A(1) | B(1) | A(2)
  issueA(0); SB;
  setB.template operator()<0>(); SB;
  issueA(1); SB;
  setB.template operator()<1>(); SB;
  issueA(2); SB;

  // iter k issues B(k+2) then A(k+3); waits for A(k),B(k); computes tap k.
  static_for<0, KT>([&]<int k>() {
    if constexpr (k + 2 < KT) { setB.template operator()<k + 2>(); }
    SB;
    if constexpr (k + 3 < KT) { issueA(k + 3); }
    SB;
    // counted wait: everything older than the 28 (24/12/0) newest VMEM ops is
    // complete -> A(k) in LDS and B(k) in regs.
    if constexpr (k <= KT - 4)      asm volatile("s_waitcnt vmcnt(28)" ::: "memory");
    else if constexpr (k == KT - 3) asm volatile("s_waitcnt vmcnt(24)" ::: "memory");
    else if constexpr (k == KT - 2) asm volatile("s_waitcnt vmcnt(12)" ::: "memory");
    else                            asm volatile("s_waitcnt vmcnt(0)"  ::: "memory");
    bf16x8 a0, a1, a2, a3;
    constexpr int sl = k & 3;
    if constexpr (sl == 0)      { DSR(a0, "0")     DSR(a1, "1024")  DSR(a2, "2048")  DSR(a3, "3072")  }
    else if constexpr (sl == 1) { DSR(a0, "4096")  DSR(a1, "5120")  DSR(a2, "6144")  DSR(a3, "7168")  }
    else if constexpr (sl == 2) { DSR(a0, "8192")  DSR(a1, "9216")  DSR(a2, "10240") DSR(a3, "11264") }
    else                        { DSR(a0, "12288") DSR(a1, "13312") DSR(a2, "14336") DSR(a3, "15360") }
    asm volatile("s_waitcnt lgkmcnt(0)" ::: "memory");
    SB;   // rule #18: keep MFMAs below the lgkm wait
    if constexpr (k % 3 == 0) compute(a0, a1, a2, a3, B0);
    else if constexpr (k % 3 == 1) compute(a0, a1, a2, a3, B1);
    else compute(a0, a1, a2, a3, B2);
  });

#undef DSR
#undef SB

  // epilogue: store h + fused per-channel stats
  // C/D (32x32): col = lane&31, row = (reg&3) + 8*(reg>>2) + 4*(lane>>5)
  const int orow0 = wbase + (hh << 2);
  float s0 = 0.f, q0 = 0.f, s1 = 0.f, q1 = 0.f;
#pragma unroll
  for (int reg = 0; reg < 16; ++reg) {
    int row = orow0 + (reg & 3) + 8 * (reg >> 2);
    float v0 = acc0[reg], v1 = acc1[reg];
    if (OBF16) {
      ushort_t* ho = (ushort_t*)houtv;
      ho[row * 64 + r31] = f2bf(v0);
      ho[row * 64 + 32 + r31] = f2bf(v1);
    } else {
      float* ho = (float*)houtv;
      ho[row * 64 + r31] = v0;
      ho[row * 64 + 32 + r31] = v1;
    }
    s0 += v0; q0 += v0 * v0;
    s1 += v1; q1 += v1 * v1;
  }
  s0 += __shfl_xor(s0, 32, 64); q0 += __shfl_xor(q0, 32, 64);
  s1 += __shfl_xor(s1, 32, 64); q1 += __shfl_xor(q1, 32, 64);
  if (hh == 0) {
    red[0][w][r31] = s0; red[0][w][32 + r31] = s1;
    red[1][w][r31] = q0; red[1][w][32 + r31] = q1;
  }
  __syncthreads();   // only barrier in the kernel
  if (t < 128) {
    int which = t >> 6, c = t & 63;
    float v = red[which][0][c] + red[which][1][c] + red[which][2][c] + red[which][3][c];
    atomicAdd((which ? gsq : gsum) + c, v);
  }
}

// BN1 (inline params from raw stats) + ReLU on bf16 h1, writes bf16 for conv2's gather
__global__ __launch_bounds__(256) void k_bn_relu(const ushort_t* __restrict__ h,
                                                 const float* __restrict__ gsum,
                                                 const float* __restrict__ gsq,
                                                 const float* __restrict__ gamma,
                                                 const float* __restrict__ beta,
                                                 ushort_t* __restrict__ ob) {
  __shared__ float sc[64], sh[64];
  int t = threadIdx.x;
  if (t < 64) {
    float mean = gsum[t] * (1.f / NV);
    float var = gsq[t] * (1.f / NV) - mean * mean;
    float rs = rsqrtf(var + 1e-5f);
    float s = gamma[t] * rs;
    sc[t] = s;
    sh[t] = beta[t] - mean * s;
  }
  __syncthreads();
  int i = blockIdx.x * 256 + t;    // uint4 index = 8 bf16
  int c0 = (i & 7) * 8;
  uint4 v = ((const uint4*)h)[i];
  const ushort_t* pu = (const ushort_t*)&v;
  uint4 o;
  ushort_t* po = (ushort_t*)&o;
#pragma unroll
  for (int n = 0; n < 8; ++n)
    po[n] = f2bf(fmaxf(0.f, b2f(pu[n]) * sc[c0 + n] + sh[c0 + n]));
  ((uint4*)ob)[i] = o;
}

// BN2 (inline params) + residual + ReLU, fp32 out
__global__ __launch_bounds__(256) void k_final(const float* __restrict__ h,
                                               const float* __restrict__ x,
                                               const float* __restrict__ gsum,
                                               const float* __restrict__ gsq,
                                               const float* __restrict__ gamma,
                                               const float* __restrict__ beta,
                                               float* __restrict__ out) {
  __shared__ float sc[64], sh[64];
  int t = threadIdx.x;
  if (t < 64) {
    float mean = gsum[t] * (1.f / NV);
    float var = gsq[t] * (1.f / NV) - mean * mean;
    float rs = rsqrtf(var + 1e-5f);
    float s = gamma[t] * rs;
    sc[t] = s;
    sh[t] = beta[t] - mean * s;
  }
  __syncthreads();
  int i = blockIdx.x * 256 + t;
  int c0 = (i << 2) & 63;
  float4 v = ((const float4*)h)[i];
  float4 xv = ((const float4*)x)[i];
  float4 o;
  o.x = fmaxf(0.f, v.x * sc[c0]     + sh[c0]     + xv.x);
  o.y = fmaxf(0.f, v.y * sc[c0 + 1] + sh[c0 + 1] + xv.y);
  o.z = fmaxf(0.f, v.z * sc[c0 + 2] + sh[c0 + 2] + xv.z);
  o.w = fmaxf(0.f, v.w * sc[c0 + 3] + sh[c0 + 3] + xv.w);
  ((float4*)out)[i] = o;
}

extern "C" void kernel_launch(void* const* d_in, const int* in_sizes, int n_in,
                              void* d_out, int out_size, void* d_ws, size_t ws_size,
                              hipStream_t stream) {
  const float* x   = (const float*)d_in[0];
  const int*   nbr = (const int*)d_in[1];
  const float* W1  = (const float*)d_in[2];
  const float* g1  = (const float*)d_in[3];
  const float* b1  = (const float*)d_in[4];
  const float* W2  = (const float*)d_in[5];
  const float* g2  = (const float*)d_in[6];
  const float* b2  = (const float*)d_in[7];
  float* out = (float*)d_out;
  char* ws = (char*)d_ws;

  // workspace layout (bytes, 256-aligned), total ~42.8 MB (+2KB stats/zero pad)
  ushort_t* xb     = (ushort_t*)(ws);               // 8,388,608
  ushort_t* h1pre  = (ushort_t*)(ws + 8388608);     // 8,388,608 (bf16, pre-BN)
  ushort_t* h1post = (ushort_t*)(ws + 16777216);    // 8,388,608 (bf16, post-BN+ReLU)
  ushort_t* Wf1    = (ushort_t*)(ws + 25165824);    // 442,368
  ushort_t* Wf2    = (ushort_t*)(ws + 25608192);    // 442,368
  float*    h2raw  = (float*)(ws + 26050560);       // 16,777,216
  float*    statsp = (float*)(ws + 42827776);       // 512 floats (stats + zero row)
  float *gsum1 = statsp, *gsq1 = statsp + 64, *gsum2 = statsp + 128, *gsq2 = statsp + 192;
  const ushort_t* zrow = (const ushort_t*)(statsp + 256);  // 1KB of zeros

  k_prep<<<5824, 256, 0, stream>>>(x, W1, W2, xb, Wf1, Wf2, statsp);

  k_conv<true><<<512, 256, 0, stream>>>(xb, nbr, Wf1, zrow, (void*)h1pre, gsum1, gsq1);
  k_bn_relu<<<2048, 256, 0, stream>>>(h1pre, gsum1, gsq1, g1, b1, h1post);
  k_conv<false><<<512, 256, 0, stream>>>(h1post, nbr, Wf2, zrow, (void*)h2raw, gsum2, gsq2);

  k_final<<<4096, 256, 0, stream>>>(h2raw, x, gsum2, gsq2, g2, b2, out);
}